// Round 1
// baseline (438.536 us; speedup 1.0000x reference)
//
#include <hip/hip_runtime.h>
#include <hip/hip_bf16.h>

typedef __bf16 bf16;
typedef __attribute__((ext_vector_type(8))) __bf16 bf16x8;
typedef __attribute__((ext_vector_type(4))) float f32x4;

#define DEV __device__ __forceinline__

// async global->LDS, 16B per lane; LDS dest = wave-uniform base + lane*16
DEV void gload_lds16(const void* g, void* l) {
  __builtin_amdgcn_global_load_lds(
      (__attribute__((address_space(1))) void*)(g),
      (__attribute__((address_space(3))) void*)(l), 16, 0, 0);
}

// ---------------- conversion kernels ----------------
// fp32 -> bf16, 8 elems/thread
__global__ void k_cvt_bf16(const float* __restrict__ in, bf16* __restrict__ out, int n8) {
  int i = blockIdx.x * blockDim.x + threadIdx.x;
  if (i >= n8) return;
  const float4* p = reinterpret_cast<const float4*>(in) + (size_t)i * 2;
  float4 a = p[0], b = p[1];
  bf16x8 o;
  o[0] = (bf16)a.x; o[1] = (bf16)a.y; o[2] = (bf16)a.z; o[3] = (bf16)a.w;
  o[4] = (bf16)b.x; o[5] = (bf16)b.y; o[6] = (bf16)b.z; o[7] = (bf16)b.w;
  *reinterpret_cast<bf16x8*>(out + (size_t)i * 8) = o;
}

// Wt[n][d] = W[h=n>>6][d][e=n&63]   (W: [16,1024,64] -> Wt: [1024,1024], bf16)
__global__ void k_cvt_wqkv(const float* __restrict__ W, bf16* __restrict__ Wt) {
  int idx = blockIdx.x * blockDim.x + threadIdx.x;  // covers 1<<20
  int d = idx & 1023, n = idx >> 10;
  Wt[idx] = (bf16)W[((size_t)(n >> 6) << 16) + (size_t)d * 64 + (n & 63)];
}

// WoT[n][k] = Wo[k][n]   (1024x1024 transpose, bf16)
__global__ void k_cvt_wo(const float* __restrict__ W, bf16* __restrict__ Wt) {
  int idx = blockIdx.x * blockDim.x + threadIdx.x;
  int k = idx & 1023, n = idx >> 10;
  Wt[idx] = (bf16)W[(size_t)k * 1024 + n];
}

// ---------------- GEMM: C = A[8192x1024] * Bt[1024x1024]^T ----------------
// m97-style: 128x128 tile, BK=32, 4 waves (2x2), 4x4 16x16x32 frags per wave.
// SMODE 0: bf16 out, scatter to [B,H,S,64]   (Q,K heads)
// SMODE 1: bf16 out, scatter to [B,H,64,S]   (V transposed; 4-row packed stores)
// SMODE 2: f32 out, plain [M][N]             (final projection -> d_out)
template <int SMODE>
__global__ __launch_bounds__(256) void k_gemm(const bf16* __restrict__ A,
                                              const bf16* __restrict__ Bt,
                                              void* __restrict__ Cout) {
  constexpr int K = 1024;
  __shared__ __align__(16) bf16 As[128 * 32];
  __shared__ __align__(16) bf16 Bs[128 * 32];
  const int tid = threadIdx.x;
  const int lane = tid & 63, w = tid >> 6;
  const int wr = w >> 1, wc = w & 1;
  const int lgrp = lane >> 4, lid = lane & 15;
  const int m0 = blockIdx.x * 128, n0 = blockIdx.y * 128;

  f32x4 acc[4][4] = {};

  // staging: 8KB tile = 8 chunks of 1KB; wave w owns chunks w*2, w*2+1
  const int c0 = w * 2, c1 = w * 2 + 1;
  const int bo0 = c0 * 1024 + lane * 16, bo1 = c1 * 1024 + lane * 16;
  const int r0 = bo0 >> 6, e0 = (bo0 & 63) >> 1;  // row, elem-in-row
  const int r1 = bo1 >> 6, e1 = (bo1 & 63) >> 1;

  for (int k0 = 0; k0 < K; k0 += 32) {
    __syncthreads();  // WAR: previous iter's frag reads done
    gload_lds16(A + (size_t)(m0 + r0) * K + k0 + e0, (char*)As + c0 * 1024);
    gload_lds16(A + (size_t)(m0 + r1) * K + k0 + e1, (char*)As + c1 * 1024);
    gload_lds16(Bt + (size_t)(n0 + r0) * K + k0 + e0, (char*)Bs + c0 * 1024);
    gload_lds16(Bt + (size_t)(n0 + r1) * K + k0 + e1, (char*)Bs + c1 * 1024);
    __syncthreads();  // compiler drains vmcnt(0) before s_barrier
    bf16x8 af[4], bfv[4];
    for (int m = 0; m < 4; ++m)
      af[m] = *reinterpret_cast<const bf16x8*>(&As[(wr * 64 + m * 16 + lid) * 32 + lgrp * 8]);
    for (int n = 0; n < 4; ++n)
      bfv[n] = *reinterpret_cast<const bf16x8*>(&Bs[(wc * 64 + n * 16 + lid) * 32 + lgrp * 8]);
    for (int m = 0; m < 4; ++m)
      for (int n = 0; n < 4; ++n)
        acc[m][n] = __builtin_amdgcn_mfma_f32_16x16x32_bf16(af[m], bfv[n], acc[m][n], 0, 0, 0);
  }

  // C layout per frag: row = (lane>>4)*4 + r, col = lane&15
  if constexpr (SMODE == 2) {
    float* C = (float*)Cout;
    for (int m = 0; m < 4; ++m) {
      int rowb = m0 + wr * 64 + m * 16 + lgrp * 4;
      for (int n = 0; n < 4; ++n) {
        int col = n0 + wc * 64 + n * 16 + lid;
        for (int r = 0; r < 4; ++r)
          C[(size_t)(rowb + r) * 1024 + col] = acc[m][n][r];
      }
    }
  } else if constexpr (SMODE == 0) {
    bf16* C = (bf16*)Cout;
    for (int m = 0; m < 4; ++m) {
      int rowb = m0 + wr * 64 + m * 16 + lgrp * 4;
      for (int n = 0; n < 4; ++n) {
        int col = n0 + wc * 64 + n * 16 + lid;
        int h = col >> 6, e = col & 63;
        for (int r = 0; r < 4; ++r) {
          int row = rowb + r;
          int b = row >> 11, s = row & 2047;
          C[(((size_t)b * 16 + h) * 2048 + s) * 64 + e] = (bf16)acc[m][n][r];
        }
      }
    }
  } else {  // SMODE 1: V^T [B,H,64,S]; 4 consecutive s per lane -> 8B packed store
    bf16* C = (bf16*)Cout;
    for (int m = 0; m < 4; ++m) {
      int rowb = m0 + wr * 64 + m * 16 + lgrp * 4;
      int b = rowb >> 11, s = rowb & 2047;  // 4-row group never crosses batch
      for (int n = 0; n < 4; ++n) {
        int col = n0 + wc * 64 + n * 16 + lid;
        int h = col >> 6, e = col & 63;
        union { bf16 hv[4]; uint2 u; } tmp;
        for (int r = 0; r < 4; ++r) tmp.hv[r] = (bf16)acc[m][n][r];
        bf16* dst = C + (((size_t)b * 16 + h) * 64 + e) * 2048 + s;
        *reinterpret_cast<uint2*>(dst) = tmp.u;
      }
    }
  }
}

// ---------------- flash attention ----------------
// Qh,Kh: [B,H,S,64] bf16; Vt: [B,H,64,S] bf16; Ob: [B,S,H*64] bf16
// block = 4 independent waves, each owns 16 q-rows; KV tile = 32 keys.
__global__ __launch_bounds__(256) void k_flash(const bf16* __restrict__ Qh,
                                               const bf16* __restrict__ Kh,
                                               const bf16* __restrict__ Vt,
                                               const int* __restrict__ valid,
                                               bf16* __restrict__ Ob) {
  __shared__ __align__(16) bf16 Plds[4][16 * 32];  // per-wave P buffer
  const int tid = threadIdx.x, lane = tid & 63, w = tid >> 6;
  const int lgrp = lane >> 4, lid = lane & 15;
  const int blk = blockIdx.x;
  const int qt = blk & 31, bh = blk >> 5;  // 32 consecutive blocks share (b,h) -> L2 reuse
  const int b = bh >> 4, h = bh & 15;
  const int s0 = qt * 64 + w * 16;
  const bf16* Qp = Qh + ((size_t)bh * 2048 + s0) * 64;
  const bf16* Kp = Kh + (size_t)bh * 2048 * 64;
  const bf16* Vp = Vt + (size_t)bh * 64 * 2048;
  const int vl = valid[b];
  const int nt = (vl + 31) >> 5;  // skip fully-masked KV tiles

  // Q A-frags (row=lid, k=lgrp*8+j), K-dim 64 = 2 chunks
  bf16x8 aq0 = *reinterpret_cast<const bf16x8*>(Qp + lid * 64 + lgrp * 8);
  bf16x8 aq1 = *reinterpret_cast<const bf16x8*>(Qp + lid * 64 + 32 + lgrp * 8);

  f32x4 Of[4] = {};
  float mrow[4] = {-1e30f, -1e30f, -1e30f, -1e30f};
  float lrow[4] = {0.f, 0.f, 0.f, 0.f};
  bf16* Pw = &Plds[w][0];

  for (int t0 = 0; t0 < nt * 32; t0 += 32) {
    // scores S[16q][32k] = Q * K^T, two 16-col frags
    f32x4 sc[2] = {};
    for (int ct = 0; ct < 2; ++ct) {
      const bf16* kp = Kp + (size_t)(t0 + ct * 16 + lid) * 64 + lgrp * 8;
      bf16x8 bk0 = *reinterpret_cast<const bf16x8*>(kp);
      bf16x8 bk1 = *reinterpret_cast<const bf16x8*>(kp + 32);
      sc[ct] = __builtin_amdgcn_mfma_f32_16x16x32_bf16(aq0, bk0, sc[ct], 0, 0, 0);
      sc[ct] = __builtin_amdgcn_mfma_f32_16x16x32_bf16(aq1, bk1, sc[ct], 0, 0, 0);
    }
    // scale 1/sqrt(64) + padding mask (col >= vl)
    for (int ct = 0; ct < 2; ++ct) {
      const bool masked = (t0 + ct * 16 + lid) >= vl;
      for (int r = 0; r < 4; ++r)
        sc[ct][r] = masked ? -1e30f : sc[ct][r] * 0.125f;
    }
    // online softmax: row = lgrp*4 + r, 16 cols spread over 16-lane group
    float scale[4];
    for (int r = 0; r < 4; ++r) {
      float vm = fmaxf(sc[0][r], sc[1][r]);
      vm = fmaxf(vm, __shfl_xor(vm, 1));
      vm = fmaxf(vm, __shfl_xor(vm, 2));
      vm = fmaxf(vm, __shfl_xor(vm, 4));
      vm = fmaxf(vm, __shfl_xor(vm, 8));
      float mnew = fmaxf(mrow[r], vm);
      scale[r] = __expf(mrow[r] - mnew);
      mrow[r] = mnew;
    }
    for (int ct = 0; ct < 2; ++ct)
      for (int r = 0; r < 4; ++r)
        sc[ct][r] = __expf(sc[ct][r] - mrow[r]);  // masked -> exp(-1e30)=0
    for (int r = 0; r < 4; ++r) {
      float s = sc[0][r] + sc[1][r];
      s += __shfl_xor(s, 1);
      s += __shfl_xor(s, 2);
      s += __shfl_xor(s, 4);
      s += __shfl_xor(s, 8);
      lrow[r] = lrow[r] * scale[r] + s;
    }
    // P: C-layout -> LDS -> A-layout (within-wave round trip, no barrier needed)
    for (int ct = 0; ct < 2; ++ct)
      for (int r = 0; r < 4; ++r)
        Pw[(lgrp * 4 + r) * 32 + ct * 16 + lid] = (bf16)sc[ct][r];
    asm volatile("s_waitcnt lgkmcnt(0)" ::: "memory");
    bf16x8 pa = *reinterpret_cast<const bf16x8*>(Pw + lid * 32 + lgrp * 8);
    // rescale O accumulator, then PV (B-operand contiguous thanks to V^T layout)
    for (int f = 0; f < 4; ++f)
      for (int r = 0; r < 4; ++r)
        Of[f][r] *= scale[r];
    for (int f = 0; f < 4; ++f) {
      bf16x8 bv = *reinterpret_cast<const bf16x8*>(Vp + (size_t)(f * 16 + lid) * 2048 + t0 + lgrp * 8);
      Of[f] = __builtin_amdgcn_mfma_f32_16x16x32_bf16(pa, bv, Of[f], 0, 0, 0);
    }
  }
  // epilogue: O/l, store bf16 to [B,S,H*64]
  bf16* Op = Ob + ((size_t)b * 2048 + s0) * 1024 + h * 64;
  for (int r = 0; r < 4; ++r) {
    float inv = 1.f / lrow[r];
    for (int f = 0; f < 4; ++f)
      Op[(size_t)(lgrp * 4 + r) * 1024 + f * 16 + lid] = (bf16)(Of[f][r] * inv);
  }
}

// ---------------- launch ----------------
extern "C" void kernel_launch(void* const* d_in, const int* in_sizes, int n_in,
                              void* d_out, int out_size, void* d_ws, size_t ws_size,
                              hipStream_t stream) {
  const float* q = (const float*)d_in[0];
  const float* k = (const float*)d_in[1];
  const float* v = (const float*)d_in[2];
  const int* vl = (const int*)d_in[3];
  const float* Wq = (const float*)d_in[4];
  const float* Wk = (const float*)d_in[5];
  const float* Wv = (const float*)d_in[6];
  const float* Wo = (const float*)d_in[7];

  char* ws = (char*)d_ws;
  const size_t SZW = (size_t)1024 * 1024 * 2;  // 2MB  (transposed bf16 weight)
  const size_t SZT = (size_t)8192 * 1024 * 2;  // 16MB (bf16 activation tensor)
  bf16* WqT = (bf16*)(ws);
  bf16* WkT = (bf16*)(ws + SZW);
  bf16* WvT = (bf16*)(ws + 2 * SZW);
  bf16* WoT = (bf16*)(ws + 3 * SZW);
  bf16* Qh  = (bf16*)(ws + 4 * SZW);
  bf16* Kh  = (bf16*)(ws + 4 * SZW + SZT);
  bf16* Vt  = (bf16*)(ws + 4 * SZW + 2 * SZT);
  bf16* qb  = (bf16*)(ws + 4 * SZW + 3 * SZT);
  bf16* kb  = (bf16*)(ws + 4 * SZW + 4 * SZT);
  bf16* vb  = (bf16*)(ws + 4 * SZW + 5 * SZT);
  bf16* attnb = qb;  // qb dead after Q projection; reuse for attention output

  k_cvt_bf16<<<4096, 256, 0, stream>>>(q, qb, 1 << 20);
  k_cvt_bf16<<<4096, 256, 0, stream>>>(k, kb, 1 << 20);
  k_cvt_bf16<<<4096, 256, 0, stream>>>(v, vb, 1 << 20);
  k_cvt_wqkv<<<4096, 256, 0, stream>>>(Wq, WqT);
  k_cvt_wqkv<<<4096, 256, 0, stream>>>(Wk, WkT);
  k_cvt_wqkv<<<4096, 256, 0, stream>>>(Wv, WvT);
  k_cvt_wo<<<4096, 256, 0, stream>>>(Wo, WoT);

  dim3 gg(64, 8);  // M/128 x N/128
  k_gemm<0><<<gg, 256, 0, stream>>>(qb, WqT, Qh);
  k_gemm<0><<<gg, 256, 0, stream>>>(kb, WkT, Kh);
  k_gemm<1><<<gg, 256, 0, stream>>>(vb, WvT, Vt);
  k_flash<<<2048, 256, 0, stream>>>(Qh, Kh, Vt, vl, attnb);
  k_gemm<2><<<gg, 256, 0, stream>>>(attnb, WoT, d_out);
}